// Round 5
// baseline (348.068 us; speedup 1.0000x reference)
//
#include <hip/hip_runtime.h>
#include <stdint.h>

#define D_MODEL 1024
#define N_HEADS 16
#define D_HEAD 64
#define BATCH 4
#define SEQ 2048
#define MTOT (BATCH * SEQ)   // 8192

typedef unsigned short u16;
typedef __attribute__((ext_vector_type(8))) short bf16x8;
typedef __attribute__((ext_vector_type(4))) float f32x4;

#define MFMA(a, b, c) __builtin_amdgcn_mfma_f32_16x16x32_bf16((a), (b), (c), 0, 0, 0)
#define LOG2E 1.4426950408889634f
#define SC (0.125f * LOG2E)   // folded into Wq at cvt time

// fp32 -> bf16 bits, round-to-nearest-even
static __device__ __forceinline__ u16 f2bf(float f) {
  unsigned u = __builtin_bit_cast(unsigned, f);
  u += 0x7fffu + ((u >> 16) & 1u);
  return (u16)(u >> 16);
}
// truncating (1 inst) — for p >= 0, error < 1 ulp
static __device__ __forceinline__ u16 f2bf_t(float f) {
  return (u16)(__builtin_bit_cast(unsigned, f) >> 16);
}

// async 16B global->LDS (dest = wave-uniform base + lane*16)
static __device__ __forceinline__ void gload_lds16(const void* g, void* l) {
  __builtin_amdgcn_global_load_lds(
      (const __attribute__((address_space(1))) void*)g,
      (__attribute__((address_space(3))) void*)l, 16, 0, 0);
}

// ---- converts ----
__global__ __launch_bounds__(256) void cvt3(const float* __restrict__ a,
                                            const float* __restrict__ b,
                                            const float* __restrict__ c,
                                            u16* __restrict__ oa, u16* __restrict__ ob,
                                            u16* __restrict__ oc) {
  const int z = blockIdx.y;
  const float* in = (z == 0) ? a : (z == 1) ? b : c;
  u16* out = (z == 0) ? oa : (z == 1) ? ob : oc;
  int i = blockIdx.x * 256 + threadIdx.x;
  float4 v = ((const float4*)in)[i];
  ushort4 o;
  o.x = f2bf(v.x); o.y = f2bf(v.y); o.z = f2bf(v.z); o.w = f2bf(v.w);
  ((ushort4*)out)[i] = o;
}

// z==0 (Wq) gets the attention scale folded in: Q' = x @ (SC*Wq)^T
__global__ __launch_bounds__(256) void cvt4(const float* __restrict__ a,
                                            const float* __restrict__ b,
                                            const float* __restrict__ c,
                                            const float* __restrict__ d,
                                            u16* __restrict__ oa, u16* __restrict__ ob,
                                            u16* __restrict__ oc, u16* __restrict__ od) {
  const int z = blockIdx.y;
  const float* in = (z == 0) ? a : (z == 1) ? b : (z == 2) ? c : d;
  u16* out = (z == 0) ? oa : (z == 1) ? ob : (z == 2) ? oc : od;
  const float s = (z == 0) ? SC : 1.0f;
  int i = blockIdx.x * 256 + threadIdx.x;
  float4 v = ((const float4*)in)[i];
  ushort4 o;
  o.x = f2bf(v.x * s); o.y = f2bf(v.y * s); o.z = f2bf(v.z * s); o.w = f2bf(v.w * s);
  ((ushort4*)out)[i] = o;
}

// ============== paced 256x256 GEMM core (C = A @ B^T), m201-style ==============
// BM=BN=256, BK=64, 512 threads = 8 waves (2M x 4N), wave-tile 128x64 (acc 8x4).
// Double-buffered LDS (128 KiB). Per K-tile: ONE vmcnt(0)+s_barrier at the top
// (cheap: only the pair issued one phase earlier is still in flight), then 4
// phases, each = { issue 2 DMA ops of tile kt+1 into the OTHER buffer |
// 4-8 ds_read_b128 | 16 MFMA under setprio }, phase edges pinned with
// sched_barrier(0). Staging into buf (kt+1)&1 during iter kt is race-free:
// the top-of-iter barrier proves every wave finished reading that buffer in
// iter kt-1. PACED issue (2 ops/wave/phase) replaces R1-R4's 48-op bursts,
// which oscillated the per-CU DMA queue (measured 11.4 B/cyc/CU vs the
// ~20 B/cyc/CU this path sustains when paced — m97/m201). 256^2 also drops
// DMA demand to 3.8 B/KFLOP (vs 11.4 at 256x128).
#define BM 256
#define BN 256
#define BK 64
#define NKT (D_MODEL / BK)   // 16
#define TSZ (256 * 64)       // u16 elements per tile buffer (A or B)

static __device__ __forceinline__ void gemm_core(const u16* __restrict__ A,
                                                 const u16* __restrict__ B,
                                                 u16* As, u16* Bs,
                                                 int m0, int n0, f32x4 acc[8][4]) {
  const int t = threadIdx.x;
  const int lane = t & 63, wave = t >> 6;
  const int wm = wave >> 2, wn = wave & 3;          // 2(M) x 4(N) wave grid
  const int lrow = lane & 15, quad = lane >> 4;
  const int srow = t >> 3;                          // 0..63: row within block-op
  const int swcol = (((t & 7) ^ (srow & 7)) << 3);  // pre-swizzled global column
  const int sdst = srow * 64 + (t & 7) * 8;         // linear LDS dest (u16)
  const int rsw = lrow & 7;                         // reader-side swizzle key

#pragma unroll
  for (int i = 0; i < 8; i++)
#pragma unroll
    for (int j = 0; j < 4; j++) acc[i][j] = (f32x4){0.f, 0.f, 0.f, 0.f};

  // block-wide stage op r_ (rows r_*64 + srow) of tile kt_ into buffer bi_
#define SA_(kt_, bi_, r_)                                                       \
  gload_lds16(A + (size_t)(m0 + (r_)*64 + srow) * 1024 + (kt_)*BK + swcol,      \
              As + (bi_)*TSZ + (r_)*4096 + sdst)
#define SB_(kt_, bi_, r_)                                                       \
  gload_lds16(B + (size_t)(n0 + (r_)*64 + srow) * 1024 + (kt_)*BK + swcol,      \
              Bs + (bi_)*TSZ + (r_)*4096 + sdst)

  // prologue: tile 0 (8 ops/wave)
#pragma unroll
  for (int r = 0; r < 4; ++r) { SA_(0, 0, r); SB_(0, 0, r); }

  for (int kt = 0; kt < NKT; ++kt) {
    // outstanding here = tile kt's 8 ops (last pair issued 1 phase ago)
    asm volatile("s_waitcnt vmcnt(0)" ::: "memory");
    __builtin_amdgcn_s_barrier();
    asm volatile("" ::: "memory");

    const u16* as = As + (kt & 1) * TSZ;
    const u16* bs = Bs + (kt & 1) * TSZ;
    const int nb = (kt + 1) & 1;
    const bool pf = (kt + 1 < NKT);
    const int cx0 = (quad ^ rsw) << 3;        // ks=0 column group
    const int cx1 = ((4 + quad) ^ rsw) << 3;  // ks=1 column group

    bf16x8 a[4], b0[4], b1[4];

    // ---- phase 0: ks0 x mh0 ----
    if (pf) { SA_(kt + 1, nb, 0); SB_(kt + 1, nb, 0); }
#pragma unroll
    for (int i = 0; i < 4; i++)
      a[i] = *(const bf16x8*)(as + (wm * 128 + i * 16 + lrow) * 64 + cx0);
#pragma unroll
    for (int j = 0; j < 4; j++)
      b0[j] = *(const bf16x8*)(bs + (wn * 64 + j * 16 + lrow) * 64 + cx0);
    __builtin_amdgcn_sched_barrier(0);
    __builtin_amdgcn_s_setprio(1);
#pragma unroll
    for (int i = 0; i < 4; i++)
#pragma unroll
      for (int j = 0; j < 4; j++) acc[i][j] = MFMA(a[i], b0[j], acc[i][j]);
    __builtin_amdgcn_s_setprio(0);
    __builtin_amdgcn_sched_barrier(0);

    // ---- phase 1: ks0 x mh1 ----
    if (pf) { SA_(kt + 1, nb, 1); SB_(kt + 1, nb, 1); }
#pragma unroll
    for (int i = 0; i < 4; i++)
      a[i] = *(const bf16x8*)(as + (wm * 128 + (i + 4) * 16 + lrow) * 64 + cx0);
    __builtin_amdgcn_sched_barrier(0);
    __builtin_amdgcn_s_setprio(1);
#pragma unroll
    for (int i = 0; i < 4; i++)
#pragma unroll
      for (int j = 0; j < 4; j++) acc[i + 4][j] = MFMA(a[i], b0[j], acc[i + 4][j]);
    __builtin_amdgcn_s_setprio(0);
    __builtin_amdgcn_sched_barrier(0);

    // ---- phase 2: ks1 x mh0 ----
    if (pf) { SA_(kt + 1, nb, 2); SB_(kt + 1, nb, 2); }
#pragma unroll
    for (int i = 0; i < 4; i++)
      a[i] = *(const bf16x8*)(as + (wm * 128 + i * 16 + lrow) * 64 + cx1);
#pragma unroll
    for (int j = 0; j < 4; j++)
      b1[j] = *(const bf16x8*)(bs + (wn * 64 + j * 16 + lrow) * 64 + cx1);
    __builtin_amdgcn_sched_barrier(0);
    __builtin_amdgcn_s_setprio(1);
#pragma unroll
    for (int i = 0; i < 4; i++)
#pragma unroll
      for (int j = 0; j < 4; j++) acc[i][j] = MFMA(a[i], b1[j], acc[i][j]);
    __builtin_amdgcn_s_setprio(0);
    __builtin_amdgcn_sched_barrier(0);

    // ---- phase 3: ks1 x mh1 ----
    if (pf) { SA_(kt + 1, nb, 3); SB_(kt + 1, nb, 3); }
#pragma unroll
    for (int i = 0; i < 4; i++)
      a[i] = *(const bf16x8*)(as + (wm * 128 + (i + 4) * 16 + lrow) * 64 + cx1);
    __builtin_amdgcn_sched_barrier(0);
    __builtin_amdgcn_s_setprio(1);
#pragma unroll
    for (int i = 0; i < 4; i++)
#pragma unroll
      for (int j = 0; j < 4; j++) acc[i + 4][j] = MFMA(a[i], b1[j], acc[i + 4][j]);
    __builtin_amdgcn_s_setprio(0);
    __builtin_amdgcn_sched_barrier(0);
  }
#undef SA_
#undef SB_
}

// ---- fused QKV projection: C = A @ W^T ----
// z=0 -> Q (scale pre-folded in Wqb); z=1 -> K; z=2 -> V TRANSPOSED [b][n][t]
__global__ __launch_bounds__(512, 2) void gemm_qkv(const u16* __restrict__ xq,
                                                   const u16* __restrict__ xk,
                                                   const u16* __restrict__ xv,
                                                   const u16* __restrict__ Wqb,
                                                   const u16* __restrict__ Wkb,
                                                   const u16* __restrict__ Wvb,
                                                   u16* __restrict__ Qb, u16* __restrict__ Kb,
                                                   u16* __restrict__ Vtg, int zbase) {
  __shared__ u16 As[2 * TSZ];   // 64 KiB
  __shared__ u16 Bs[2 * TSZ];   // 64 KiB
  const int z = blockIdx.z + zbase;
  const u16* A = (z == 0) ? xq : (z == 1) ? xk : xv;
  const u16* B = (z == 0) ? Wqb : (z == 1) ? Wkb : Wvb;
  const int m0 = blockIdx.x * BM, n0 = blockIdx.y * BN;

  f32x4 acc[8][4];
  gemm_core(A, B, As, Bs, m0, n0, acc);

  const int lane = threadIdx.x & 63, wave = threadIdx.x >> 6;
  const int wm = wave >> 2, wn = wave & 3;
  const int lrow = lane & 15, quad = lane >> 4;

  // C/D: col = lane&15 (n), row = quad*4 + reg (m)
  if (z == 2) {
    const int b = m0 >> 11;
    const int t0 = (m0 & 2047);
#pragma unroll
    for (int i = 0; i < 8; i++) {
      const int trow = t0 + wm * 128 + i * 16 + quad * 4;
#pragma unroll
      for (int j = 0; j < 4; j++) {
        const int n = n0 + wn * 64 + j * 16 + lrow;
        ushort4 pk;
        pk.x = f2bf(acc[i][j][0]); pk.y = f2bf(acc[i][j][1]);
        pk.z = f2bf(acc[i][j][2]); pk.w = f2bf(acc[i][j][3]);
        *(ushort4*)(Vtg + (size_t)b * D_MODEL * SEQ + (size_t)n * SEQ + trow) = pk;
      }
    }
  } else {
    u16* C = z ? Kb : Qb;
#pragma unroll
    for (int i = 0; i < 8; i++) {
      const int mr = m0 + wm * 128 + i * 16 + quad * 4;
#pragma unroll
      for (int j = 0; j < 4; j++) {
        const int n = n0 + wn * 64 + j * 16 + lrow;
#pragma unroll
        for (int r = 0; r < 4; r++) C[(size_t)(mr + r) * 1024 + n] = f2bf(acc[i][j][r]);
      }
    }
  }
}

// ---- output projection: f32 out ----
__global__ __launch_bounds__(512, 2) void gemm_o(const u16* __restrict__ A,
                                                 const u16* __restrict__ B,
                                                 float* __restrict__ C) {
  __shared__ u16 As[2 * TSZ];
  __shared__ u16 Bs[2 * TSZ];
  const int m0 = blockIdx.x * BM, n0 = blockIdx.y * BN;

  f32x4 acc[8][4];
  gemm_core(A, B, As, Bs, m0, n0, acc);

  const int lane = threadIdx.x & 63, wave = threadIdx.x >> 6;
  const int wm = wave >> 2, wn = wave & 3;
  const int lrow = lane & 15, quad = lane >> 4;
#pragma unroll
  for (int i = 0; i < 8; i++) {
    const int mr = m0 + wm * 128 + i * 16 + quad * 4;
#pragma unroll
    for (int j = 0; j < 4; j++) {
      const int n = n0 + wn * 64 + j * 16 + lrow;
#pragma unroll
      for (int r = 0; r < 4; r++) C[(size_t)(mr + r) * 1024 + n] = acc[i][j][r];
    }
  }
}

// ---- causal flash attention, v4: triple-buffered K/V, counted vmcnt ----
// (unchanged this round)
__global__ __launch_bounds__(256) void attn_causal(const u16* __restrict__ Qb,
                                                   const u16* __restrict__ Kb,
                                                   const u16* __restrict__ Vtg,
                                                   u16* __restrict__ Ob) {
  __shared__ u16 QPs[128 * 64];   // 16 KB: Q staging, then P
  __shared__ u16 Ks[3 * 64 * 64]; // 24 KB
  __shared__ u16 Vs[3 * 64 * 64]; // 24 KB  V^T tiles [d][j]

  const int t = threadIdx.x;
  const int lane = t & 63, wave = t >> 6;
  const int lrow = lane & 15, quad = lane >> 4;
  const int wb = wave * 32;
  const int bh = blockIdx.x;
  const int b = bh >> 4, h = bh & 15;
  const int col0 = h * 64;
  const size_t rowbase = (size_t)b * SEQ;
  const size_t vbase = (size_t)b * (size_t)D_MODEL * SEQ;
  const int srow = t >> 3;
  const int swcol = (((t & 7) ^ (srow & 7)) << 3);
  const int pchunk = (t & 7) * 8;
  const int rsw = lrow & 7;

  // stage K/V tile kt_ into buffer bi_: 4 DMA ops per wave
#define KVSTAGE_(kt_, bi_)                                                      \
  do {                                                                          \
    const int j0_ = (kt_)*64;                                                   \
    u16* ks_ = Ks + (bi_)*4096;                                                 \
    u16* vs_ = Vs + (bi_)*4096;                                                 \
    _Pragma("unroll") for (int r_ = 0; r_ < 2; ++r_) {                          \
      int rr_ = r_ * 32 + srow;                                                 \
      gload_lds16(Kb + (rowbase + j0_ + rr_) * D_MODEL + col0 + swcol,          \
                  ks_ + rr_ * 64 + pchunk);                                     \
      gload_lds16(Vtg + vbase + (size_t)(col0 + rr_) * SEQ + j0_ + swcol,       \
                  vs_ + rr_ * 64 + pchunk);                                     \
    }                                                                           \
  } while (0)

  // ones B-column (n=0): lanes with lrow==0 hold 1.0 in all k slots
  bf16x8 bOnes;
  {
    const short ov = (lrow == 0) ? (short)0x3F80 : (short)0;
#pragma unroll
    for (int e = 0; e < 8; ++e) bOnes[e] = ov;
  }

  for (int part = 0; part < 2; ++part) {
    const int qt = part ? (15 - (int)blockIdx.y) : (int)blockIdx.y;
    const int qrow0 = qt * 128;
    const int nkt = 2 * qt + 2;   // >= 2

    // stage Q tile (4 DMA), then K/V tiles 0 and 1 (4 DMA each)
#pragma unroll
    for (int r = 0; r < 4; ++r) {
      int rr = r * 32 + srow;
      gload_lds16(Qb + (rowbase + qrow0 + rr) * D_MODEL + col0 + swcol,
                  QPs + rr * 64 + pchunk);
    }
    KVSTAGE_(0, 0);
    KVSTAGE_(1, 1);

    bf16x8 bQ[2][2];     // Q fragments in registers (loop-invariant)
    f32x4 oacc[2][4];    // O[m][d]: [mf][df]
    f32x4 lacc[2];       // l at col 0
#pragma unroll
    for (int mf = 0; mf < 2; mf++) {
#pragma unroll
      for (int df = 0; df < 4; df++) oacc[mf][df] = (f32x4){0.f, 0.f, 0.f, 0.f};
      lacc[mf] = (f32x4){0.f, 0.f, 0.f, 0.f};
    }

    for (int kt = 0; kt < nkt; ++kt) {
      // tile kt's 4 DMA are the oldest in flight; kt+1's 4 stay in flight.
      // (At kt==0 this also retires the Q-stage DMA, issued before tile 0.)
      if (kt < nkt - 1) asm volatile("s_waitcnt vmcnt(4)" ::: "memory");
      else              asm volatile("s_waitcnt vmcnt(0)" ::: "memory");
      __builtin_amdgcn_s_barrier();
      asm volatile("" ::: "memory");

      if (kt + 2 < nkt) KVSTAGE_(kt + 2, (kt + 2) % 3);  // overlaps compute

      const u16* ksb = Ks + (kt % 3) * 4096;
      const u16* vsb = Vs + (kt % 3) * 4096;

      if (kt == 0) {
#pragma unroll
        for (int mf = 0; mf < 2; ++mf)
#pragma unroll
          for (int ks = 0; ks < 2; ++ks)
            bQ[mf][ks] = *(const bf16x8*)(QPs + (wb + mf * 16 + lrow) * 64 +
                                          (((ks * 4 + quad) ^ rsw) << 3));
      }

      const int j0 = kt * 64;
      const bool diag = (kt >= 2 * qt);
      // S^T = K·Q^T per mf half; softmax; P -> QPs (ushort4, swizzled)
#pragma unroll
      for (int mf = 0; mf < 2; ++mf) {
        f32x4 st[4];
#pragma unroll
        for (int jf = 0; jf < 4; jf++) st[jf] = (f32x4){0.f, 0.f, 0.f, 0.f};
#pragma unroll
        for (int ks = 0; ks < 2; ++ks) {
          const int cx = ((ks * 4 + quad) ^ rsw) << 3;
#pragma unroll
          for (int jf = 0; jf < 4; jf++) {
            bf16x8 aK = *(const bf16x8*)(ksb + (jf * 16 + lrow) * 64 + cx);
            st[jf] = MFMA(aK, bQ[mf][ks], st[jf]);
          }
        }
        // st[jf] rows: j = j0 + jf*16 + quad*4 + r ; col: m = wb + mf*16 + lrow
        const int m = wb + mf * 16 + lrow;
        const int gm = qrow0 + m;
#pragma unroll
        for (int jf = 0; jf < 4; jf++) {
          ushort4 pk;
#pragma unroll
          for (int r = 0; r < 4; r++) {
            float p = __builtin_amdgcn_exp2f(st[jf][r]);  // scale pre-folded
            const int gj = j0 + jf * 16 + quad * 4 + r;
            if (diag && gj > gm) p = 0.f;
            ((u16*)&pk)[r] = f2bf_t(p);
          }
          const int j = jf * 16 + quad * 4;
          *(ushort4*)(QPs + m * 64 + ((((j >> 3) ^ (m & 7)) << 3) | (j & 7))) = pk;
        }
      }

      // O += P·V^T ; l += P·1  (QPs rows are wave-private: no barrier)
#pragma unroll
      for (int ks = 0; ks < 2; ++ks) {
        const int cx = ((ks * 4 + quad) ^ rsw) << 3;  // (m&7)==rsw for our rows
        bf16x8 aP[2];
#pragma unroll
        for (int mf = 0; mf < 2; ++mf)
          aP[mf] = *(const bf16x8*)(QPs + (wb + mf * 16 + lrow) * 64 + cx);
        lacc[0] = MFMA(aP[0], bOnes, lacc[0]);
        lacc[1] = MFMA(aP[1], bOnes, lacc[1]);
#pragma unroll
        for (int df = 0; df < 4; df++) {
          bf16x8 bV = *(const bf16x8*)(vsb + (df * 16 + lrow) * 64 + cx);
          oacc[0][df] = MFMA(aP[0], bV, oacc[0][df]);
          oacc[1][df] = MFMA(aP[1], bV, oacc[1][df]);
        }
      }
      __builtin_amdgcn_sched_barrier(0);  // pin iteration edge (buffer-free proof)
    }
    __syncthreads();  // all waves done with QPs/Ks/Vs before next part restages

    // l[m = quad*4+r] sits in lacc[mf][r] at lane quad*16 (col 0)
    float linv[2][4];
#pragma unroll
    for (int mf = 0; mf < 2; mf++)
#pragma unroll
      for (int r = 0; r < 4; r++)
        linv[mf][r] = 1.0f / __shfl(lacc[mf][r], lane & 48);

    // store O: row = qrow0 + wb + mf*16 + quad*4 + r, col = col0 + df*16 + lrow
#pragma unroll
    for (int mf = 0; mf < 2; mf++)
#pragma unroll
      for (int r = 0; r < 4; r++) {
        u16* orow = Ob + (rowbase + qrow0 + wb + mf * 16 + quad * 4 + r) * D_MODEL + col0;
#pragma unroll
        for (int df = 0; df < 4; df++)
          orow[df * 16 + lrow] = f2bf(oacc[mf][df][r] * linv[mf][r]);
      }
  }
#undef KVSTAGE_
}

extern "C" void kernel_launch(void* const* d_in, const int* in_sizes, int n_in,
                              void* d_out, int out_size, void* d_ws, size_t ws_size,
                              hipStream_t stream) {
  const float* q  = (const float*)d_in[0];
  const float* k  = (const float*)d_in[1];
  const float* v  = (const float*)d_in[2];
  // d_in[3] = mask — strict-upper-triangle causal; handled analytically
  const float* Wq = (const float*)d_in[4];
  const float* Wk = (const float*)d_in[5];
  const float* Wv = (const float*)d_in[6];
  const float* Wo = (const float*)d_in[7];
  float* out = (float*)d_out;

  char* ws = (char*)d_ws;
  const size_t MB = 1 << 20;
  u16* xq  = (u16*)(ws);
  u16* xk  = (u16*)(ws + 16 * MB);
  u16* xv  = (u16*)(ws + 32 * MB);
  u16* Wqb = (u16*)(ws + 48 * MB);
  u16* Wkb = (u16*)(ws + 50 * MB);
  u16* Wvb = (u16*)(ws + 52 * MB);
  u16* Wob = (u16*)(ws + 54 * MB);
  u16* Qb  = (u16*)(ws + 56 * MB);

  const dim3 cb(256);
  const dim3 gb(512);
  cvt3<<<dim3(MTOT * D_MODEL / 4 / 256, 3), cb, 0, stream>>>(q, k, v, xq, xk, xv);
  cvt4<<<dim3(D_MODEL * D_MODEL / 4 / 256, 4), cb, 0, stream>>>(Wq, Wk, Wv, Wo,
                                                                Wqb, Wkb, Wvb, Wob);

  if (ws_size >= 104 * MB) {
    u16* Kb  = (u16*)(ws + 72 * MB);
    u16* Vtg = (u16*)(ws + 88 * MB);
    gemm_qkv<<<dim3(32, 4, 3), gb, 0, stream>>>(xq, xk, xv, Wqb, Wkb, Wvb,
                                                Qb, Kb, Vtg, 0);
    attn_causal<<<dim3(64, 8), cb, 0, stream>>>(Qb, Kb, Vtg, xq);  // O -> xq
    gemm_o<<<dim3(32, 4), gb, 0, stream>>>(xq, Wob, out);
  } else {
    u16* Kb  = (u16*)(ws);
    u16* Vtg = (u16*)(ws + 16 * MB);
    u16* Oatt = (u16*)(ws + 32 * MB);
    gemm_qkv<<<dim3(32, 4, 1), gb, 0, stream>>>(xq, xq, xq, Wqb, Wqb, Wqb,
                                                Qb, Qb, Qb, 0);
    gemm_qkv<<<dim3(32, 4, 1), gb, 0, stream>>>(xk, xk, xk, Wkb, Wkb, Wkb,
                                                Kb, Kb, Kb, 1);
    gemm_qkv<<<dim3(32, 4, 1), gb, 0, stream>>>(xv, xv, xv, Wvb, Wvb, Wvb,
                                                Vtg, Vtg, Vtg, 2);
    attn_causal<<<dim3(64, 8), cb, 0, stream>>>(Qb, Kb, Vtg, Oatt);
    gemm_o<<<dim3(32, 4), gb, 0, stream>>>(Oatt, Wob, out);
  }
}

// Round 6
// 341.048 us; speedup vs baseline: 1.0206x; 1.0206x over previous
//
#include <hip/hip_runtime.h>
#include <stdint.h>

#define D_MODEL 1024
#define N_HEADS 16
#define D_HEAD 64
#define BATCH 4
#define SEQ 2048
#define MTOT (BATCH * SEQ)   // 8192

typedef unsigned short u16;
typedef __attribute__((ext_vector_type(8))) short bf16x8;
typedef __attribute__((ext_vector_type(4))) float f32x4;

#define MFMA(a, b, c) __builtin_amdgcn_mfma_f32_16x16x32_bf16((a), (b), (c), 0, 0, 0)
#define LOG2E 1.4426950408889634f
#define SC (0.125f * LOG2E)   // folded into Wq at cvt time

// fp32 -> bf16 bits, round-to-nearest-even
static __device__ __forceinline__ u16 f2bf(float f) {
  unsigned u = __builtin_bit_cast(unsigned, f);
  u += 0x7fffu + ((u >> 16) & 1u);
  return (u16)(u >> 16);
}
// truncating (1 inst) — for p >= 0, error < 1 ulp
static __device__ __forceinline__ u16 f2bf_t(float f) {
  return (u16)(__builtin_bit_cast(unsigned, f) >> 16);
}
// HW packed f32x2 -> bf16x2 (RNE), one instruction (T12 recipe; no builtin)
static __device__ __forceinline__ unsigned cvtpk(float lo, float hi) {
  unsigned r;
  asm volatile("v_cvt_pk_bf16_f32 %0, %1, %2" : "=v"(r) : "v"(lo), "v"(hi));
  return r;
}

// async 16B global->LDS (dest = wave-uniform base + lane*16)
static __device__ __forceinline__ void gload_lds16(const void* g, void* l) {
  __builtin_amdgcn_global_load_lds(
      (const __attribute__((address_space(1))) void*)g,
      (__attribute__((address_space(3))) void*)l, 16, 0, 0);
}

// ---- weight converts (q/k/v conversion is fused into gemm_qkv's A-staging) ----
// z==0 (Wq) gets the attention scale folded in: Q' = x @ (SC*Wq)^T
__global__ __launch_bounds__(256) void cvt4(const float* __restrict__ a,
                                            const float* __restrict__ b,
                                            const float* __restrict__ c,
                                            const float* __restrict__ d,
                                            u16* __restrict__ oa, u16* __restrict__ ob,
                                            u16* __restrict__ oc, u16* __restrict__ od) {
  const int z = blockIdx.y;
  const float* in = (z == 0) ? a : (z == 1) ? b : (z == 2) ? c : d;
  u16* out = (z == 0) ? oa : (z == 1) ? ob : (z == 2) ? oc : od;
  const float s = (z == 0) ? SC : 1.0f;
  int i = blockIdx.x * 256 + threadIdx.x;
  float4 v = ((const float4*)in)[i];
  ushort4 o;
  o.x = f2bf(v.x * s); o.y = f2bf(v.y * s); o.z = f2bf(v.z * s); o.w = f2bf(v.w * s);
  ((ushort4*)out)[i] = o;
}

// ================= GEMM geometry (R2 config — measured best, 76.1 µs) ========
// BM=256 x BN=128 x BK=64, 512 threads = 8 waves (4M x 2N), per-wave 64x64.
#define BM 256
#define BN 128
#define BK 64
#define NKT (D_MODEL / BK)   // 16
#define ASZ (BM * BK)        // u16 elements per A tile buffer
#define BSZ (BN * BK)

// ---- bf16-A core (verbatim R2: dbuf, counted vmcnt(6), dedup reads) ----
static __device__ __forceinline__ void gemm_core(const u16* __restrict__ A,
                                                 const u16* __restrict__ B,
                                                 u16* As, u16* Bs,
                                                 int m0, int n0, f32x4 acc[4][4]) {
  const int t = threadIdx.x;
  const int lane = t & 63, wave = t >> 6;
  const int wm = wave >> 1, wn = wave & 1;          // 4 x 2 wave grid
  const int lrow = lane & 15, quad = lane >> 4;
  const int srow = t >> 3;                          // 0..63: staged row within issue
  const int swcol = (((t & 7) ^ (srow & 7)) << 3);  // pre-swizzled global column
  const int sdst = srow * 64 + (t & 7) * 8;         // linear LDS dest (u16)
  const int rsw = lrow & 7;                         // reader-side swizzle key

#pragma unroll
  for (int i = 0; i < 4; i++)
#pragma unroll
    for (int j = 0; j < 4; j++) acc[i][j] = (f32x4){0.f, 0.f, 0.f, 0.f};

#define STAGE_(kt_, bi_)                                                        \
  do {                                                                          \
    const int k0_ = (kt_)*BK;                                                   \
    u16* as_ = As + (bi_)*ASZ;                                                  \
    u16* bs_ = Bs + (bi_)*BSZ;                                                  \
    _Pragma("unroll") for (int r_ = 0; r_ < 4; ++r_)                            \
        gload_lds16(A + (size_t)(m0 + r_ * 64 + srow) * 1024 + k0_ + swcol,     \
                    as_ + r_ * 64 * 64 + sdst);                                 \
    _Pragma("unroll") for (int r_ = 0; r_ < 2; ++r_)                            \
        gload_lds16(B + (size_t)(n0 + r_ * 64 + srow) * 1024 + k0_ + swcol,     \
                    bs_ + r_ * 64 * 64 + sdst);                                 \
  } while (0)

  STAGE_(0, 0);
  STAGE_(1, 1);

  for (int kt = 0; kt < NKT; ++kt) {
    if (kt < NKT - 1) asm volatile("s_waitcnt vmcnt(6)" ::: "memory");
    else              asm volatile("s_waitcnt vmcnt(0)" ::: "memory");
    __builtin_amdgcn_s_barrier();
    asm volatile("" ::: "memory");

    const u16* as = As + (kt & 1) * ASZ;
    const u16* bs = Bs + (kt & 1) * BSZ;

#pragma unroll
    for (int ks = 0; ks < 2; ++ks) {
      const int cx = ((ks * 4 + quad) ^ rsw) << 3;
      bf16x8 a[4], b[4];
#pragma unroll
      for (int i = 0; i < 4; i++)
        a[i] = *(const bf16x8*)(as + (wm * 64 + i * 16 + lrow) * 64 + cx);
#pragma unroll
      for (int j = 0; j < 4; j++)
        b[j] = *(const bf16x8*)(bs + (wn * 64 + j * 16 + lrow) * 64 + cx);
      __builtin_amdgcn_s_setprio(1);
#pragma unroll
      for (int i = 0; i < 4; i++)
#pragma unroll
        for (int j = 0; j < 4; j++) acc[i][j] = MFMA(a[i], b[j], acc[i][j]);
      __builtin_amdgcn_s_setprio(0);
    }

    if (kt + 2 < NKT) {
      asm volatile("" ::: "memory");
      __builtin_amdgcn_sched_barrier(0);
      __builtin_amdgcn_s_barrier();
      STAGE_(kt + 2, kt & 1);
    }
  }
#undef STAGE_
}

// ---- f32-A fused core: A loaded as f32, converted in-register (RNE), written
// to the SAME swizzled LDS layout the DMA path used. T14 split: loads issued
// at iter top (pinned), cvt+ds_write after the compute phase — MFMA hides the
// HBM latency. B stays on global_load_lds. Removes the cvt3 pre-pass. ----
static __device__ __forceinline__ void gemm_core_f32A(const float* __restrict__ A,
                                                      const u16* __restrict__ B,
                                                      u16* As, u16* Bs,
                                                      int m0, int n0, f32x4 acc[4][4]) {
  const int t = threadIdx.x;
  const int lane = t & 63, wave = t >> 6;
  const int wm = wave >> 1, wn = wave & 1;
  const int lrow = lane & 15, quad = lane >> 4;
  const int srow = t >> 3;
  const int swcol = (((t & 7) ^ (srow & 7)) << 3);
  const int sdst = srow * 64 + (t & 7) * 8;
  const int rsw = lrow & 7;

#pragma unroll
  for (int i = 0; i < 4; i++)
#pragma unroll
    for (int j = 0; j < 4; j++) acc[i][j] = (f32x4){0.f, 0.f, 0.f, 0.f};

  float4 af[4][2];   // 8 floats/lane per staged row-group = cols swcol..swcol+7

#define ALOAD_(kt_)                                                             \
  do {                                                                          \
    _Pragma("unroll") for (int r_ = 0; r_ < 4; ++r_) {                          \
      const float* ap_ = A + (size_t)(m0 + r_ * 64 + srow) * 1024 + (kt_)*BK + swcol; \
      af[r_][0] = *(const float4*)ap_;                                          \
      af[r_][1] = *(const float4*)(ap_ + 4);                                    \
    }                                                                           \
  } while (0)

#define AWRITE_(bi_)                                                            \
  do {                                                                          \
    _Pragma("unroll") for (int r_ = 0; r_ < 4; ++r_) {                          \
      uint4 w_;                                                                 \
      w_.x = cvtpk(af[r_][0].x, af[r_][0].y);                                   \
      w_.y = cvtpk(af[r_][0].z, af[r_][0].w);                                   \
      w_.z = cvtpk(af[r_][1].x, af[r_][1].y);                                   \
      w_.w = cvtpk(af[r_][1].z, af[r_][1].w);                                   \
      *(uint4*)(As + (bi_)*ASZ + r_ * 4096 + sdst) = w_;                        \
    }                                                                           \
  } while (0)

#define BSTAGE_(kt_, bi_)                                                       \
  do {                                                                          \
    _Pragma("unroll") for (int r_ = 0; r_ < 2; ++r_)                            \
        gload_lds16(B + (size_t)(n0 + r_ * 64 + srow) * 1024 + (kt_)*BK + swcol,\
                    Bs + (bi_)*BSZ + r_ * 4096 + sdst);                         \
  } while (0)

  // prologue: tile 0 staged fully (one-time)
  ALOAD_(0);
  BSTAGE_(0, 0);
  AWRITE_(0);          // compiler waits the A loads; B DMA drained by sync below
  __syncthreads();

  for (int kt = 0; kt < NKT; ++kt) {
    const bool pf = (kt + 1 < NKT);
    // issue-early: next tile's A loads + B DMA, pinned so they can't sink
    if (pf) { ALOAD_(kt + 1); BSTAGE_(kt + 1, (kt + 1) & 1); }
    __builtin_amdgcn_sched_barrier(0);

    const u16* as = As + (kt & 1) * ASZ;
    const u16* bs = Bs + (kt & 1) * BSZ;

#pragma unroll
    for (int ks = 0; ks < 2; ++ks) {
      const int cx = ((ks * 4 + quad) ^ rsw) << 3;
      bf16x8 a[4], b[4];
#pragma unroll
      for (int i = 0; i < 4; i++)
        a[i] = *(const bf16x8*)(as + (wm * 64 + i * 16 + lrow) * 64 + cx);
#pragma unroll
      for (int j = 0; j < 4; j++)
        b[j] = *(const bf16x8*)(bs + (wn * 64 + j * 16 + lrow) * 64 + cx);
      __builtin_amdgcn_s_setprio(1);
#pragma unroll
      for (int i = 0; i < 4; i++)
#pragma unroll
        for (int j = 0; j < 4; j++) acc[i][j] = MFMA(a[i], b[j], acc[i][j]);
      __builtin_amdgcn_s_setprio(0);
    }

    // write-late: convert + deposit next A tile (opposite buffer from 'as')
    if (pf) AWRITE_((kt + 1) & 1);
    __syncthreads();   // drains B DMA + ds_writes; separates buffer reuse
  }
#undef ALOAD_
#undef AWRITE_
#undef BSTAGE_
}

// ---- fused QKV projection: C = X_f32 @ W^T (conversion fused into staging) --
// z=0 -> Q (scale pre-folded in Wqb); z=1 -> K; z=2 -> V TRANSPOSED [b][n][t]
__global__ __launch_bounds__(512, 2) void gemm_qkv(const float* __restrict__ q,
                                                   const float* __restrict__ k,
                                                   const float* __restrict__ v,
                                                   const u16* __restrict__ Wqb,
                                                   const u16* __restrict__ Wkb,
                                                   const u16* __restrict__ Wvb,
                                                   u16* __restrict__ Qb, u16* __restrict__ Kb,
                                                   u16* __restrict__ Vtg) {
  __shared__ u16 As[2 * ASZ];   // 64 KiB
  __shared__ u16 Bs[2 * BSZ];   // 32 KiB
  const int z = blockIdx.z;
  const float* A = (z == 0) ? q : (z == 1) ? k : v;
  const u16* B = (z == 0) ? Wqb : (z == 1) ? Wkb : Wvb;
  const int m0 = blockIdx.x * BM, n0 = blockIdx.y * BN;

  f32x4 acc[4][4];
  gemm_core_f32A(A, B, As, Bs, m0, n0, acc);

  const int lane = threadIdx.x & 63, wave = threadIdx.x >> 6;
  const int wm = wave >> 1, wn = wave & 1;
  const int lrow = lane & 15, quad = lane >> 4;

  // C/D: col = lane&15 (n), row = quad*4 + reg (m)
  if (z == 2) {
    const int b = m0 >> 11;
    const int t0 = (m0 & 2047);
#pragma unroll
    for (int i = 0; i < 4; i++) {
      const int trow = t0 + wm * 64 + i * 16 + quad * 4;
#pragma unroll
      for (int j = 0; j < 4; j++) {
        const int n = n0 + wn * 64 + j * 16 + lrow;
        ushort4 pk;
        pk.x = f2bf(acc[i][j][0]); pk.y = f2bf(acc[i][j][1]);
        pk.z = f2bf(acc[i][j][2]); pk.w = f2bf(acc[i][j][3]);
        *(ushort4*)(Vtg + (size_t)b * D_MODEL * SEQ + (size_t)n * SEQ + trow) = pk;
      }
    }
  } else {
    u16* C = z ? Kb : Qb;
#pragma unroll
    for (int i = 0; i < 4; i++) {
      const int mr = m0 + wm * 64 + i * 16 + quad * 4;
#pragma unroll
      for (int j = 0; j < 4; j++) {
        const int n = n0 + wn * 64 + j * 16 + lrow;
#pragma unroll
        for (int r = 0; r < 4; r++) C[(size_t)(mr + r) * 1024 + n] = f2bf(acc[i][j][r]);
      }
    }
  }
}

// ---- output projection: f32 out (bf16 A from attn; R2 core) ----
__global__ __launch_bounds__(512, 2) void gemm_o(const u16* __restrict__ A,
                                                 const u16* __restrict__ B,
                                                 float* __restrict__ C) {
  __shared__ u16 As[2 * ASZ];
  __shared__ u16 Bs[2 * BSZ];
  const int m0 = blockIdx.x * BM, n0 = blockIdx.y * BN;

  f32x4 acc[4][4];
  gemm_core(A, B, As, Bs, m0, n0, acc);

  const int lane = threadIdx.x & 63, wave = threadIdx.x >> 6;
  const int wm = wave >> 1, wn = wave & 1;
  const int lrow = lane & 15, quad = lane >> 4;
#pragma unroll
  for (int i = 0; i < 4; i++) {
    const int mr = m0 + wm * 64 + i * 16 + quad * 4;
#pragma unroll
    for (int j = 0; j < 4; j++) {
      const int n = n0 + wn * 64 + j * 16 + lrow;
#pragma unroll
      for (int r = 0; r < 4; r++) C[(size_t)(mr + r) * 1024 + n] = acc[i][j][r];
    }
  }
}

// ---- causal flash attention, v4: triple-buffered K/V, counted vmcnt ----
// (unchanged this round)
__global__ __launch_bounds__(256) void attn_causal(const u16* __restrict__ Qb,
                                                   const u16* __restrict__ Kb,
                                                   const u16* __restrict__ Vtg,
                                                   u16* __restrict__ Ob) {
  __shared__ u16 QPs[128 * 64];   // 16 KB: Q staging, then P
  __shared__ u16 Ks[3 * 64 * 64]; // 24 KB
  __shared__ u16 Vs[3 * 64 * 64]; // 24 KB  V^T tiles [d][j]

  const int t = threadIdx.x;
  const int lane = t & 63, wave = t >> 6;
  const int lrow = lane & 15, quad = lane >> 4;
  const int wb = wave * 32;
  const int bh = blockIdx.x;
  const int b = bh >> 4, h = bh & 15;
  const int col0 = h * 64;
  const size_t rowbase = (size_t)b * SEQ;
  const size_t vbase = (size_t)b * (size_t)D_MODEL * SEQ;
  const int srow = t >> 3;
  const int swcol = (((t & 7) ^ (srow & 7)) << 3);
  const int pchunk = (t & 7) * 8;
  const int rsw = lrow & 7;

#define KVSTAGE_(kt_, bi_)                                                      \
  do {                                                                          \
    const int j0_ = (kt_)*64;                                                   \
    u16* ks_ = Ks + (bi_)*4096;                                                 \
    u16* vs_ = Vs + (bi_)*4096;                                                 \
    _Pragma("unroll") for (int r_ = 0; r_ < 2; ++r_) {                          \
      int rr_ = r_ * 32 + srow;                                                 \
      gload_lds16(Kb + (rowbase + j0_ + rr_) * D_MODEL + col0 + swcol,          \
                  ks_ + rr_ * 64 + pchunk);                                     \
      gload_lds16(Vtg + vbase + (size_t)(col0 + rr_) * SEQ + j0_ + swcol,       \
                  vs_ + rr_ * 64 + pchunk);                                     \
    }                                                                           \
  } while (0)

  bf16x8 bOnes;
  {
    const short ov = (lrow == 0) ? (short)0x3F80 : (short)0;
#pragma unroll
    for (int e = 0; e < 8; ++e) bOnes[e] = ov;
  }

  for (int part = 0; part < 2; ++part) {
    const int qt = part ? (15 - (int)blockIdx.y) : (int)blockIdx.y;
    const int qrow0 = qt * 128;
    const int nkt = 2 * qt + 2;   // >= 2

#pragma unroll
    for (int r = 0; r < 4; ++r) {
      int rr = r * 32 + srow;
      gload_lds16(Qb + (rowbase + qrow0 + rr) * D_MODEL + col0 + swcol,
                  QPs + rr * 64 + pchunk);
    }
    KVSTAGE_(0, 0);
    KVSTAGE_(1, 1);

    bf16x8 bQ[2][2];
    f32x4 oacc[2][4];
    f32x4 lacc[2];
#pragma unroll
    for (int mf = 0; mf < 2; mf++) {
#pragma unroll
      for (int df = 0; df < 4; df++) oacc[mf][df] = (f32x4){0.f, 0.f, 0.f, 0.f};
      lacc[mf] = (f32x4){0.f, 0.f, 0.f, 0.f};
    }

    for (int kt = 0; kt < nkt; ++kt) {
      if (kt < nkt - 1) asm volatile("s_waitcnt vmcnt(4)" ::: "memory");
      else              asm volatile("s_waitcnt vmcnt(0)" ::: "memory");
      __builtin_amdgcn_s_barrier();
      asm volatile("" ::: "memory");

      if (kt + 2 < nkt) KVSTAGE_(kt + 2, (kt + 2) % 3);

      const u16* ksb = Ks + (kt % 3) * 4096;
      const u16* vsb = Vs + (kt % 3) * 4096;

      if (kt == 0) {
#pragma unroll
        for (int mf = 0; mf < 2; ++mf)
#pragma unroll
          for (int ks = 0; ks < 2; ++ks)
            bQ[mf][ks] = *(const bf16x8*)(QPs + (wb + mf * 16 + lrow) * 64 +
                                          (((ks * 4 + quad) ^ rsw) << 3));
      }

      const int j0 = kt * 64;
      const bool diag = (kt >= 2 * qt);
#pragma unroll
      for (int mf = 0; mf < 2; ++mf) {
        f32x4 st[4];
#pragma unroll
        for (int jf = 0; jf < 4; jf++) st[jf] = (f32x4){0.f, 0.f, 0.f, 0.f};
#pragma unroll
        for (int ks = 0; ks < 2; ++ks) {
          const int cx = ((ks * 4 + quad) ^ rsw) << 3;
#pragma unroll
          for (int jf = 0; jf < 4; jf++) {
            bf16x8 aK = *(const bf16x8*)(ksb + (jf * 16 + lrow) * 64 + cx);
            st[jf] = MFMA(aK, bQ[mf][ks], st[jf]);
          }
        }
        const int m = wb + mf * 16 + lrow;
        const int gm = qrow0 + m;
#pragma unroll
        for (int jf = 0; jf < 4; jf++) {
          ushort4 pk;
#pragma unroll
          for (int r = 0; r < 4; r++) {
            float p = __builtin_amdgcn_exp2f(st[jf][r]);
            const int gj = j0 + jf * 16 + quad * 4 + r;
            if (diag && gj > gm) p = 0.f;
            ((u16*)&pk)[r] = f2bf_t(p);
          }
          const int j = jf * 16 + quad * 4;
          *(ushort4*)(QPs + m * 64 + ((((j >> 3) ^ (m & 7)) << 3) | (j & 7))) = pk;
        }
      }

#pragma unroll
      for (int ks = 0; ks < 2; ++ks) {
        const int cx = ((ks * 4 + quad) ^ rsw) << 3;
        bf16x8 aP[2];
#pragma unroll
        for (int mf = 0; mf < 2; ++mf)
          aP[mf] = *(const bf16x8*)(QPs + (wb + mf * 16 + lrow) * 64 + cx);
        lacc[0] = MFMA(aP[0], bOnes, lacc[0]);
        lacc[1] = MFMA(aP[1], bOnes, lacc[1]);
#pragma unroll
        for (int df = 0; df < 4; df++) {
          bf16x8 bV = *(const bf16x8*)(vsb + (df * 16 + lrow) * 64 + cx);
          oacc[0][df] = MFMA(aP[0], bV, oacc[0][df]);
          oacc[1][df] = MFMA(aP[1], bV, oacc[1][df]);
        }
      }
      __builtin_amdgcn_sched_barrier(0);
    }
    __syncthreads();

    float linv[2][4];
#pragma unroll
    for (int mf = 0; mf < 2; mf++)
#pragma unroll
      for (int r = 0; r < 4; r++)
        linv[mf][r] = 1.0f / __shfl(lacc[mf][r], lane & 48);

#pragma unroll
    for (int mf = 0; mf < 2; mf++)
#pragma unroll
      for (int r = 0; r < 4; r++) {
        u16* orow = Ob + (rowbase + qrow0 + wb + mf * 16 + quad * 4 + r) * D_MODEL + col0;
#pragma unroll
        for (int df = 0; df < 4; df++)
          orow[df * 16 + lrow] = f2bf(oacc[mf][df][r] * linv[mf][r]);
      }
  }
#undef KVSTAGE_
}

extern "C" void kernel_launch(void* const* d_in, const int* in_sizes, int n_in,
                              void* d_out, int out_size, void* d_ws, size_t ws_size,
                              hipStream_t stream) {
  const float* q  = (const float*)d_in[0];
  const float* k  = (const float*)d_in[1];
  const float* v  = (const float*)d_in[2];
  // d_in[3] = mask — strict-upper-triangle causal; handled analytically
  const float* Wq = (const float*)d_in[4];
  const float* Wk = (const float*)d_in[5];
  const float* Wv = (const float*)d_in[6];
  const float* Wo = (const float*)d_in[7];
  float* out = (float*)d_out;

  char* ws = (char*)d_ws;
  const size_t MB = 1 << 20;
  // layout (72 MB total): Kb 0-16, Vtg 16-32, Oatt 32-48, weights 48-56, Qb 56-72
  u16* Kb   = (u16*)(ws);
  u16* Vtg  = (u16*)(ws + 16 * MB);
  u16* Oatt = (u16*)(ws + 32 * MB);
  u16* Wqb  = (u16*)(ws + 48 * MB);
  u16* Wkb  = (u16*)(ws + 50 * MB);
  u16* Wvb  = (u16*)(ws + 52 * MB);
  u16* Wob  = (u16*)(ws + 54 * MB);
  u16* Qb   = (u16*)(ws + 56 * MB);

  const dim3 cb(256);
  const dim3 gb(512);
  cvt4<<<dim3(D_MODEL * D_MODEL / 4 / 256, 4), cb, 0, stream>>>(Wq, Wk, Wv, Wo,
                                                                Wqb, Wkb, Wvb, Wob);
  gemm_qkv<<<dim3(32, 8, 3), gb, 0, stream>>>(q, k, v, Wqb, Wkb, Wvb, Qb, Kb, Vtg);
  attn_causal<<<dim3(64, 8), cb, 0, stream>>>(Qb, Kb, Vtg, Oatt);
  gemm_o<<<dim3(32, 8), gb, 0, stream>>>(Oatt, Wob, out);
}

// Round 7
// 327.378 us; speedup vs baseline: 1.0632x; 1.0418x over previous
//
#include <hip/hip_runtime.h>
#include <stdint.h>

#define D_MODEL 1024
#define N_HEADS 16
#define D_HEAD 64
#define BATCH 4
#define SEQ 2048
#define MTOT (BATCH * SEQ)   // 8192

typedef unsigned short u16;
typedef __attribute__((ext_vector_type(8))) short bf16x8;
typedef __attribute__((ext_vector_type(4))) float f32x4;

#define MFMA(a, b, c) __builtin_amdgcn_mfma_f32_16x16x32_bf16((a), (b), (c), 0, 0, 0)
#define LOG2E 1.4426950408889634f
#define SC (0.125f * LOG2E)   // folded into Wq at cvt time

// fp32 -> bf16 bits, round-to-nearest-even
static __device__ __forceinline__ u16 f2bf(float f) {
  unsigned u = __builtin_bit_cast(unsigned, f);
  u += 0x7fffu + ((u >> 16) & 1u);
  return (u16)(u >> 16);
}
// truncating (1 inst) — for p >= 0, error < 1 ulp
static __device__ __forceinline__ u16 f2bf_t(float f) {
  return (u16)(__builtin_bit_cast(unsigned, f) >> 16);
}

// async 16B global->LDS (dest = wave-uniform base + lane*16)
static __device__ __forceinline__ void gload_lds16(const void* g, void* l) {
  __builtin_amdgcn_global_load_lds(
      (const __attribute__((address_space(1))) void*)g,
      (__attribute__((address_space(3))) void*)l, 16, 0, 0);
}

// ---- converts ----
__global__ __launch_bounds__(256) void cvt3(const float* __restrict__ a,
                                            const float* __restrict__ b,
                                            const float* __restrict__ c,
                                            u16* __restrict__ oa, u16* __restrict__ ob,
                                            u16* __restrict__ oc) {
  const int z = blockIdx.y;
  const float* in = (z == 0) ? a : (z == 1) ? b : c;
  u16* out = (z == 0) ? oa : (z == 1) ? ob : oc;
  int i = blockIdx.x * 256 + threadIdx.x;
  float4 v = ((const float4*)in)[i];
  ushort4 o;
  o.x = f2bf(v.x); o.y = f2bf(v.y); o.z = f2bf(v.z); o.w = f2bf(v.w);
  ((ushort4*)out)[i] = o;
}

// z==0 (Wq) gets the attention scale folded in: Q' = x @ (SC*Wq)^T
__global__ __launch_bounds__(256) void cvt4(const float* __restrict__ a,
                                            const float* __restrict__ b,
                                            const float* __restrict__ c,
                                            const float* __restrict__ d,
                                            u16* __restrict__ oa, u16* __restrict__ ob,
                                            u16* __restrict__ oc, u16* __restrict__ od) {
  const int z = blockIdx.y;
  const float* in = (z == 0) ? a : (z == 1) ? b : (z == 2) ? c : d;
  u16* out = (z == 0) ? oa : (z == 1) ? ob : (z == 2) ? oc : od;
  const float s = (z == 0) ? SC : 1.0f;
  int i = blockIdx.x * 256 + threadIdx.x;
  float4 v = ((const float4*)in)[i];
  ushort4 o;
  o.x = f2bf(v.x * s); o.y = f2bf(v.y * s); o.z = f2bf(v.z * s); o.w = f2bf(v.w * s);
  ((ushort4*)out)[i] = o;
}

// ================= R2 GEMM core (measured best: 76.1 µs for QKV) =============
// BM=256 x BN=128 x BK=64, 512 threads = 8 waves (4M x 2N), per-wave 64x64.
// Double-buffered LDS, counted vmcnt(6), dedup'd fragment reads.
#define BM 256
#define BN 128
#define BK 64
#define NKT (D_MODEL / BK)   // 16
#define ASZ (BM * BK)
#define BSZ (BN * BK)

static __device__ __forceinline__ void gemm_core(const u16* __restrict__ A,
                                                 const u16* __restrict__ B,
                                                 u16* As, u16* Bs,
                                                 int m0, int n0, f32x4 acc[4][4]) {
  const int t = threadIdx.x;
  const int lane = t & 63, wave = t >> 6;
  const int wm = wave >> 1, wn = wave & 1;          // 4 x 2 wave grid
  const int lrow = lane & 15, quad = lane >> 4;
  const int srow = t >> 3;
  const int swcol = (((t & 7) ^ (srow & 7)) << 3);
  const int sdst = srow * 64 + (t & 7) * 8;
  const int rsw = lrow & 7;

#pragma unroll
  for (int i = 0; i < 4; i++)
#pragma unroll
    for (int j = 0; j < 4; j++) acc[i][j] = (f32x4){0.f, 0.f, 0.f, 0.f};

#define STAGE_(kt_, bi_)                                                        \
  do {                                                                          \
    const int k0_ = (kt_)*BK;                                                   \
    u16* as_ = As + (bi_)*ASZ;                                                  \
    u16* bs_ = Bs + (bi_)*BSZ;                                                  \
    _Pragma("unroll") for (int r_ = 0; r_ < 4; ++r_)                            \
        gload_lds16(A + (size_t)(m0 + r_ * 64 + srow) * 1024 + k0_ + swcol,     \
                    as_ + r_ * 64 * 64 + sdst);                                 \
    _Pragma("unroll") for (int r_ = 0; r_ < 2; ++r_)                            \
        gload_lds16(B + (size_t)(n0 + r_ * 64 + srow) * 1024 + k0_ + swcol,     \
                    bs_ + r_ * 64 * 64 + sdst);                                 \
  } while (0)

  STAGE_(0, 0);
  STAGE_(1, 1);

  for (int kt = 0; kt < NKT; ++kt) {
    if (kt < NKT - 1) asm volatile("s_waitcnt vmcnt(6)" ::: "memory");
    else              asm volatile("s_waitcnt vmcnt(0)" ::: "memory");
    __builtin_amdgcn_s_barrier();
    asm volatile("" ::: "memory");

    const u16* as = As + (kt & 1) * ASZ;
    const u16* bs = Bs + (kt & 1) * BSZ;

#pragma unroll
    for (int ks = 0; ks < 2; ++ks) {
      const int cx = ((ks * 4 + quad) ^ rsw) << 3;
      bf16x8 a[4], b[4];
#pragma unroll
      for (int i = 0; i < 4; i++)
        a[i] = *(const bf16x8*)(as + (wm * 64 + i * 16 + lrow) * 64 + cx);
#pragma unroll
      for (int j = 0; j < 4; j++)
        b[j] = *(const bf16x8*)(bs + (wn * 64 + j * 16 + lrow) * 64 + cx);
      __builtin_amdgcn_s_setprio(1);
#pragma unroll
      for (int i = 0; i < 4; i++)
#pragma unroll
        for (int j = 0; j < 4; j++) acc[i][j] = MFMA(a[i], b[j], acc[i][j]);
      __builtin_amdgcn_s_setprio(0);
    }

    if (kt + 2 < NKT) {
      asm volatile("" ::: "memory");
      __builtin_amdgcn_sched_barrier(0);
      __builtin_amdgcn_s_barrier();
      STAGE_(kt + 2, kt & 1);
    }
  }
#undef STAGE_
}

// ---- fused QKV projection: C = A @ W^T ----
// Launched as THREE 256-block dispatches (zbase 0/1/2) — one full CU round
// each; same total work, but lets rocprof's top-5 surface attn/gemm_o.
__global__ __launch_bounds__(512, 2) void gemm_qkv(const u16* __restrict__ xq,
                                                   const u16* __restrict__ xk,
                                                   const u16* __restrict__ xv,
                                                   const u16* __restrict__ Wqb,
                                                   const u16* __restrict__ Wkb,
                                                   const u16* __restrict__ Wvb,
                                                   u16* __restrict__ Qb, u16* __restrict__ Kb,
                                                   u16* __restrict__ Vtg, int zbase) {
  __shared__ u16 As[2 * ASZ];   // 64 KiB
  __shared__ u16 Bs[2 * BSZ];   // 32 KiB
  const int z = blockIdx.z + zbase;
  const u16* A = (z == 0) ? xq : (z == 1) ? xk : xv;
  const u16* B = (z == 0) ? Wqb : (z == 1) ? Wkb : Wvb;
  const int m0 = blockIdx.x * BM, n0 = blockIdx.y * BN;

  f32x4 acc[4][4];
  gemm_core(A, B, As, Bs, m0, n0, acc);

  const int lane = threadIdx.x & 63, wave = threadIdx.x >> 6;
  const int wm = wave >> 1, wn = wave & 1;
  const int lrow = lane & 15, quad = lane >> 4;

  // C/D: col = lane&15 (n), row = quad*4 + reg (m)
  if (z == 2) {
    const int b = m0 >> 11;
    const int t0 = (m0 & 2047);
#pragma unroll
    for (int i = 0; i < 4; i++) {
      const int trow = t0 + wm * 64 + i * 16 + quad * 4;
#pragma unroll
      for (int j = 0; j < 4; j++) {
        const int n = n0 + wn * 64 + j * 16 + lrow;
        ushort4 pk;
        pk.x = f2bf(acc[i][j][0]); pk.y = f2bf(acc[i][j][1]);
        pk.z = f2bf(acc[i][j][2]); pk.w = f2bf(acc[i][j][3]);
        *(ushort4*)(Vtg + (size_t)b * D_MODEL * SEQ + (size_t)n * SEQ + trow) = pk;
      }
    }
  } else {
    u16* C = z ? Kb : Qb;
#pragma unroll
    for (int i = 0; i < 4; i++) {
      const int mr = m0 + wm * 64 + i * 16 + quad * 4;
#pragma unroll
      for (int j = 0; j < 4; j++) {
        const int n = n0 + wn * 64 + j * 16 + lrow;
#pragma unroll
        for (int r = 0; r < 4; r++) C[(size_t)(mr + r) * 1024 + n] = f2bf(acc[i][j][r]);
      }
    }
  }
}

// ---- output projection: f32 out — ROUND-0 BASELINE 128^2 kernel (verbatim).
// Evidence: R0 total 313.7 @ qkv 81.5 vs R2 total 320.1 @ qkv 76.1 ⇒ this
// kernel is ~12 µs faster than the 256x128 core for the O-projection shape.
__global__ __launch_bounds__(256) void gemm_o(const u16* __restrict__ A,
                                              const u16* __restrict__ B,
                                              float* __restrict__ C) {
  __shared__ u16 As[128 * 64];
  __shared__ u16 Bs[128 * 64];
  const int t = threadIdx.x;
  const int lane = t & 63, wave = t >> 6;
  const int wm = wave & 1, wn = wave >> 1;
  const int lrow = lane & 15, quad = lane >> 4;
  const int m0 = blockIdx.x * 128, n0 = blockIdx.y * 128;
  const int srow = t >> 3;
  const int swcol = (((t & 7) ^ (srow & 7)) << 3);
  const int rsw = lrow & 7;

  f32x4 acc[4][4];
#pragma unroll
  for (int i = 0; i < 4; i++)
#pragma unroll
    for (int j = 0; j < 4; j++) acc[i][j] = (f32x4){0.f, 0.f, 0.f, 0.f};

  for (int k0 = 0; k0 < 1024; k0 += 64) {
#pragma unroll
    for (int r = 0; r < 4; ++r) {
      int rr = r * 32 + srow;
      gload_lds16(A + (size_t)(m0 + rr) * 1024 + k0 + swcol, As + rr * 64 + (t & 7) * 8);
      gload_lds16(B + (size_t)(n0 + rr) * 1024 + k0 + swcol, Bs + rr * 64 + (t & 7) * 8);
    }
    __syncthreads();
#pragma unroll
    for (int ks = 0; ks < 2; ++ks) {
      const int cx = ((ks * 4 + quad) ^ rsw) << 3;
      bf16x8 a[4], b[4];
#pragma unroll
      for (int i = 0; i < 4; i++)
        a[i] = *(const bf16x8*)(As + (wm * 64 + i * 16 + lrow) * 64 + cx);
#pragma unroll
      for (int j = 0; j < 4; j++)
        b[j] = *(const bf16x8*)(Bs + (wn * 64 + j * 16 + lrow) * 64 + cx);
#pragma unroll
      for (int i = 0; i < 4; i++)
#pragma unroll
        for (int j = 0; j < 4; j++) acc[i][j] = MFMA(a[i], b[j], acc[i][j]);
    }
    __syncthreads();
  }
#pragma unroll
  for (int i = 0; i < 4; i++) {
    const int mr = m0 + wm * 64 + i * 16 + quad * 4;
#pragma unroll
    for (int j = 0; j < 4; j++) {
      const int n = n0 + wn * 64 + j * 16 + lrow;
#pragma unroll
      for (int r = 0; r < 4; r++) C[(size_t)(mr + r) * 1024 + n] = acc[i][j][r];
    }
  }
}

// ---- causal flash attention, v4 + T5 setprio around MFMA clusters ----
__global__ __launch_bounds__(256) void attn_causal(const u16* __restrict__ Qb,
                                                   const u16* __restrict__ Kb,
                                                   const u16* __restrict__ Vtg,
                                                   u16* __restrict__ Ob) {
  __shared__ u16 QPs[128 * 64];   // 16 KB: Q staging, then P
  __shared__ u16 Ks[3 * 64 * 64]; // 24 KB
  __shared__ u16 Vs[3 * 64 * 64]; // 24 KB  V^T tiles [d][j]

  const int t = threadIdx.x;
  const int lane = t & 63, wave = t >> 6;
  const int lrow = lane & 15, quad = lane >> 4;
  const int wb = wave * 32;
  const int bh = blockIdx.x;
  const int b = bh >> 4, h = bh & 15;
  const int col0 = h * 64;
  const size_t rowbase = (size_t)b * SEQ;
  const size_t vbase = (size_t)b * (size_t)D_MODEL * SEQ;
  const int srow = t >> 3;
  const int swcol = (((t & 7) ^ (srow & 7)) << 3);
  const int pchunk = (t & 7) * 8;
  const int rsw = lrow & 7;

#define KVSTAGE_(kt_, bi_)                                                      \
  do {                                                                          \
    const int j0_ = (kt_)*64;                                                   \
    u16* ks_ = Ks + (bi_)*4096;                                                 \
    u16* vs_ = Vs + (bi_)*4096;                                                 \
    _Pragma("unroll") for (int r_ = 0; r_ < 2; ++r_) {                          \
      int rr_ = r_ * 32 + srow;                                                 \
      gload_lds16(Kb + (rowbase + j0_ + rr_) * D_MODEL + col0 + swcol,          \
                  ks_ + rr_ * 64 + pchunk);                                     \
      gload_lds16(Vtg + vbase + (size_t)(col0 + rr_) * SEQ + j0_ + swcol,       \
                  vs_ + rr_ * 64 + pchunk);                                     \
    }                                                                           \
  } while (0)

  bf16x8 bOnes;
  {
    const short ov = (lrow == 0) ? (short)0x3F80 : (short)0;
#pragma unroll
    for (int e = 0; e < 8; ++e) bOnes[e] = ov;
  }

  for (int part = 0; part < 2; ++part) {
    const int qt = part ? (15 - (int)blockIdx.y) : (int)blockIdx.y;
    const int qrow0 = qt * 128;
    const int nkt = 2 * qt + 2;   // >= 2

#pragma unroll
    for (int r = 0; r < 4; ++r) {
      int rr = r * 32 + srow;
      gload_lds16(Qb + (rowbase + qrow0 + rr) * D_MODEL + col0 + swcol,
                  QPs + rr * 64 + pchunk);
    }
    KVSTAGE_(0, 0);
    KVSTAGE_(1, 1);

    bf16x8 bQ[2][2];
    f32x4 oacc[2][4];
    f32x4 lacc[2];
#pragma unroll
    for (int mf = 0; mf < 2; mf++) {
#pragma unroll
      for (int df = 0; df < 4; df++) oacc[mf][df] = (f32x4){0.f, 0.f, 0.f, 0.f};
      lacc[mf] = (f32x4){0.f, 0.f, 0.f, 0.f};
    }

    for (int kt = 0; kt < nkt; ++kt) {
      if (kt < nkt - 1) asm volatile("s_waitcnt vmcnt(4)" ::: "memory");
      else              asm volatile("s_waitcnt vmcnt(0)" ::: "memory");
      __builtin_amdgcn_s_barrier();
      asm volatile("" ::: "memory");

      if (kt + 2 < nkt) KVSTAGE_(kt + 2, (kt + 2) % 3);

      const u16* ksb = Ks + (kt % 3) * 4096;
      const u16* vsb = Vs + (kt % 3) * 4096;

      if (kt == 0) {
#pragma unroll
        for (int mf = 0; mf < 2; ++mf)
#pragma unroll
          for (int ks = 0; ks < 2; ++ks)
            bQ[mf][ks] = *(const bf16x8*)(QPs + (wb + mf * 16 + lrow) * 64 +
                                          (((ks * 4 + quad) ^ rsw) << 3));
      }

      const int j0 = kt * 64;
      const bool diag = (kt >= 2 * qt);
#pragma unroll
      for (int mf = 0; mf < 2; ++mf) {
        f32x4 st[4];
#pragma unroll
        for (int jf = 0; jf < 4; jf++) st[jf] = (f32x4){0.f, 0.f, 0.f, 0.f};
        __builtin_amdgcn_s_setprio(1);
#pragma unroll
        for (int ks = 0; ks < 2; ++ks) {
          const int cx = ((ks * 4 + quad) ^ rsw) << 3;
#pragma unroll
          for (int jf = 0; jf < 4; jf++) {
            bf16x8 aK = *(const bf16x8*)(ksb + (jf * 16 + lrow) * 64 + cx);
            st[jf] = MFMA(aK, bQ[mf][ks], st[jf]);
          }
        }
        __builtin_amdgcn_s_setprio(0);
        const int m = wb + mf * 16 + lrow;
        const int gm = qrow0 + m;
#pragma unroll
        for (int jf = 0; jf < 4; jf++) {
          ushort4 pk;
#pragma unroll
          for (int r = 0; r < 4; r++) {
            float p = __builtin_amdgcn_exp2f(st[jf][r]);
            const int gj = j0 + jf * 16 + quad * 4 + r;
            if (diag && gj > gm) p = 0.f;
            ((u16*)&pk)[r] = f2bf_t(p);
          }
          const int j = jf * 16 + quad * 4;
          *(ushort4*)(QPs + m * 64 + ((((j >> 3) ^ (m & 7)) << 3) | (j & 7))) = pk;
        }
      }

#pragma unroll
      for (int ks = 0; ks < 2; ++ks) {
        const int cx = ((ks * 4 + quad) ^ rsw) << 3;
        bf16x8 aP[2];
#pragma unroll
        for (int mf = 0; mf < 2; ++mf)
          aP[mf] = *(const bf16x8*)(QPs + (wb + mf * 16 + lrow) * 64 + cx);
        __builtin_amdgcn_s_setprio(1);
        lacc[0] = MFMA(aP[0], bOnes, lacc[0]);
        lacc[1] = MFMA(aP[1], bOnes, lacc[1]);
#pragma unroll
        for (int df = 0; df < 4; df++) {
          bf16x8 bV = *(const bf16x8*)(vsb + (df * 16 + lrow) * 64 + cx);
          oacc[0][df] = MFMA(aP[0], bV, oacc[0][df]);
          oacc[1][df] = MFMA(aP[1], bV, oacc[1][df]);
        }
        __builtin_amdgcn_s_setprio(0);
      }
      __builtin_amdgcn_sched_barrier(0);
    }
    __syncthreads();

    float linv[2][4];
#pragma unroll
    for (int mf = 0; mf < 2; mf++)
#pragma unroll
      for (int r = 0; r < 4; r++)
        linv[mf][r] = 1.0f / __shfl(lacc[mf][r], lane & 48);

#pragma unroll
    for (int mf = 0; mf < 2; mf++)
#pragma unroll
      for (int r = 0; r < 4; r++) {
        u16* orow = Ob + (rowbase + qrow0 + wb + mf * 16 + quad * 4 + r) * D_MODEL + col0;
#pragma unroll
        for (int df = 0; df < 4; df++)
          orow[df * 16 + lrow] = f2bf(oacc[mf][df][r] * linv[mf][r]);
      }
  }
#undef KVSTAGE_
}

extern "C" void kernel_launch(void* const* d_in, const int* in_sizes, int n_in,
                              void* d_out, int out_size, void* d_ws, size_t ws_size,
                              hipStream_t stream) {
  const float* q  = (const float*)d_in[0];
  const float* k  = (const float*)d_in[1];
  const float* v  = (const float*)d_in[2];
  // d_in[3] = mask — strict-upper-triangle causal; handled analytically
  const float* Wq = (const float*)d_in[4];
  const float* Wk = (const float*)d_in[5];
  const float* Wv = (const float*)d_in[6];
  const float* Wo = (const float*)d_in[7];
  float* out = (float*)d_out;

  char* ws = (char*)d_ws;
  const size_t MB = 1 << 20;
  u16* xq  = (u16*)(ws);
  u16* xk  = (u16*)(ws + 16 * MB);
  u16* xv  = (u16*)(ws + 32 * MB);
  u16* Wqb = (u16*)(ws + 48 * MB);
  u16* Wkb = (u16*)(ws + 50 * MB);
  u16* Wvb = (u16*)(ws + 52 * MB);
  u16* Wob = (u16*)(ws + 54 * MB);
  u16* Qb  = (u16*)(ws + 56 * MB);

  const dim3 cb(256);
  const dim3 gb(512);
  cvt3<<<dim3(MTOT * D_MODEL / 4 / 256, 3), cb, 0, stream>>>(q, k, v, xq, xk, xv);
  cvt4<<<dim3(D_MODEL * D_MODEL / 4 / 256, 4), cb, 0, stream>>>(Wq, Wk, Wv, Wo,
                                                                Wqb, Wkb, Wvb, Wob);

  if (ws_size >= 104 * MB) {
    u16* Kb  = (u16*)(ws + 72 * MB);
    u16* Vtg = (u16*)(ws + 88 * MB);
    // three 256-block dispatches (exactly one CU round each)
    gemm_qkv<<<dim3(32, 8, 1), gb, 0, stream>>>(xq, xk, xv, Wqb, Wkb, Wvb,
                                                Qb, Kb, Vtg, 0);
    gemm_qkv<<<dim3(32, 8, 1), gb, 0, stream>>>(xq, xk, xv, Wqb, Wkb, Wvb,
                                                Qb, Kb, Vtg, 1);
    gemm_qkv<<<dim3(32, 8, 1), gb, 0, stream>>>(xq, xk, xv, Wqb, Wkb, Wvb,
                                                Qb, Kb, Vtg, 2);
    attn_causal<<<dim3(64, 8), cb, 0, stream>>>(Qb, Kb, Vtg, xq);  // O -> xq
    gemm_o<<<dim3(64, 8), cb, 0, stream>>>(xq, Wob, out);
  } else {
    u16* Kb  = (u16*)(ws);
    u16* Vtg = (u16*)(ws + 16 * MB);
    u16* Oatt = (u16*)(ws + 32 * MB);
    gemm_qkv<<<dim3(32, 8, 1), gb, 0, stream>>>(xq, xq, xq, Wqb, Wqb, Wqb,
                                                Qb, Qb, Qb, 0);
    gemm_qkv<<<dim3(32, 8, 1), gb, 0, stream>>>(xk, xk, xk, Wkb, Wkb, Wkb,
                                                Kb, Kb, Kb, 1);
    gemm_qkv<<<dim3(32, 8, 1), gb, 0, stream>>>(xv, xv, xv, Wvb, Wvb, Wvb,
                                                Vtg, Vtg, Vtg, 2);
    attn_causal<<<dim3(64, 8), cb, 0, stream>>>(Qb, Kb, Vtg, Oatt);
    gemm_o<<<dim3(64, 8), cb, 0, stream>>>(Oatt, Wob, out);
  }
}

// Round 8
// 314.629 us; speedup vs baseline: 1.1063x; 1.0405x over previous
//
#include <hip/hip_runtime.h>
#include <stdint.h>

#define D_MODEL 1024
#define N_HEADS 16
#define D_HEAD 64
#define BATCH 4
#define SEQ 2048
#define MTOT (BATCH * SEQ)   // 8192

typedef unsigned short u16;
typedef __attribute__((ext_vector_type(8))) short bf16x8;
typedef __attribute__((ext_vector_type(4))) float f32x4;

#define MFMA(a, b, c) __builtin_amdgcn_mfma_f32_16x16x32_bf16((a), (b), (c), 0, 0, 0)
#define LOG2E 1.4426950408889634f
#define SC (0.125f * LOG2E)   // folded into Wq at cvt time

// fp32 -> bf16 bits, round-to-nearest-even
static __device__ __forceinline__ u16 f2bf(float f) {
  unsigned u = __builtin_bit_cast(unsigned, f);
  u += 0x7fffu + ((u >> 16) & 1u);
  return (u16)(u >> 16);
}
// truncating (1 inst) — for p >= 0, error < 1 ulp
static __device__ __forceinline__ u16 f2bf_t(float f) {
  return (u16)(__builtin_bit_cast(unsigned, f) >> 16);
}

// async 16B global->LDS (dest = wave-uniform base + lane*16)
static __device__ __forceinline__ void gload_lds16(const void* g, void* l) {
  __builtin_amdgcn_global_load_lds(
      (const __attribute__((address_space(1))) void*)g,
      (__attribute__((address_space(3))) void*)l, 16, 0, 0);
}

// ---- single fused convert kernel (saves one launch; gaps are ~7-10 µs) ----
// blocks 0..24575: q/k/v (8192 each); 24576..28671: Wq/Wk/Wv/Wo (1024 each).
// Wq gets SC folded in. (*1.0f is exact for the rest.)
__global__ __launch_bounds__(256) void cvt_all(const float* __restrict__ q,
                                               const float* __restrict__ k,
                                               const float* __restrict__ v,
                                               const float* __restrict__ Wq,
                                               const float* __restrict__ Wk,
                                               const float* __restrict__ Wv,
                                               const float* __restrict__ Wo,
                                               u16* __restrict__ xq, u16* __restrict__ xk,
                                               u16* __restrict__ xv,
                                               u16* __restrict__ Wqb, u16* __restrict__ Wkb,
                                               u16* __restrict__ Wvb, u16* __restrict__ Wob) {
  const int gid = blockIdx.x;
  const float* in;
  u16* out;
  float s = 1.0f;
  int i;
  if (gid < 24576) {
    const int z = gid >> 13;
    in = (z == 0) ? q : (z == 1) ? k : v;
    out = (z == 0) ? xq : (z == 1) ? xk : xv;
    i = (gid & 8191) * 256 + threadIdx.x;
  } else {
    const int g = gid - 24576;
    const int z = g >> 10;
    in = (z == 0) ? Wq : (z == 1) ? Wk : (z == 2) ? Wv : Wo;
    out = (z == 0) ? Wqb : (z == 1) ? Wkb : (z == 2) ? Wvb : Wob;
    if (z == 0) s = SC;
    i = (g & 1023) * 256 + threadIdx.x;
  }
  float4 vv = ((const float4*)in)[i];
  ushort4 o;
  o.x = f2bf(vv.x * s); o.y = f2bf(vv.y * s); o.z = f2bf(vv.z * s); o.w = f2bf(vv.w * s);
  ((ushort4*)out)[i] = o;
}

// ================= R2 GEMM core (measured best: 76.1 µs for QKV) =============
// BM=256 x BN=128 x BK=64, 512 threads = 8 waves (4M x 2N), per-wave 64x64.
// Double-buffered LDS, counted vmcnt(6), dedup'd fragment reads.
#define BM 256
#define BN 128
#define BK 64
#define NKT (D_MODEL / BK)   // 16
#define ASZ (BM * BK)
#define BSZ (BN * BK)

static __device__ __forceinline__ void gemm_core(const u16* __restrict__ A,
                                                 const u16* __restrict__ B,
                                                 u16* As, u16* Bs,
                                                 int m0, int n0, f32x4 acc[4][4]) {
  const int t = threadIdx.x;
  const int lane = t & 63, wave = t >> 6;
  const int wm = wave >> 1, wn = wave & 1;          // 4 x 2 wave grid
  const int lrow = lane & 15, quad = lane >> 4;
  const int srow = t >> 3;
  const int swcol = (((t & 7) ^ (srow & 7)) << 3);
  const int sdst = srow * 64 + (t & 7) * 8;
  const int rsw = lrow & 7;

#pragma unroll
  for (int i = 0; i < 4; i++)
#pragma unroll
    for (int j = 0; j < 4; j++) acc[i][j] = (f32x4){0.f, 0.f, 0.f, 0.f};

#define STAGE_(kt_, bi_)                                                        \
  do {                                                                          \
    const int k0_ = (kt_)*BK;                                                   \
    u16* as_ = As + (bi_)*ASZ;                                                  \
    u16* bs_ = Bs + (bi_)*BSZ;                                                  \
    _Pragma("unroll") for (int r_ = 0; r_ < 4; ++r_)                            \
        gload_lds16(A + (size_t)(m0 + r_ * 64 + srow) * 1024 + k0_ + swcol,     \
                    as_ + r_ * 64 * 64 + sdst);                                 \
    _Pragma("unroll") for (int r_ = 0; r_ < 2; ++r_)                            \
        gload_lds16(B + (size_t)(n0 + r_ * 64 + srow) * 1024 + k0_ + swcol,     \
                    bs_ + r_ * 64 * 64 + sdst);                                 \
  } while (0)

  STAGE_(0, 0);
  STAGE_(1, 1);

  for (int kt = 0; kt < NKT; ++kt) {
    if (kt < NKT - 1) asm volatile("s_waitcnt vmcnt(6)" ::: "memory");
    else              asm volatile("s_waitcnt vmcnt(0)" ::: "memory");
    __builtin_amdgcn_s_barrier();
    asm volatile("" ::: "memory");

    const u16* as = As + (kt & 1) * ASZ;
    const u16* bs = Bs + (kt & 1) * BSZ;

#pragma unroll
    for (int ks = 0; ks < 2; ++ks) {
      const int cx = ((ks * 4 + quad) ^ rsw) << 3;
      bf16x8 a[4], b[4];
#pragma unroll
      for (int i = 0; i < 4; i++)
        a[i] = *(const bf16x8*)(as + (wm * 64 + i * 16 + lrow) * 64 + cx);
#pragma unroll
      for (int j = 0; j < 4; j++)
        b[j] = *(const bf16x8*)(bs + (wn * 64 + j * 16 + lrow) * 64 + cx);
      __builtin_amdgcn_s_setprio(1);
#pragma unroll
      for (int i = 0; i < 4; i++)
#pragma unroll
        for (int j = 0; j < 4; j++) acc[i][j] = MFMA(a[i], b[j], acc[i][j]);
      __builtin_amdgcn_s_setprio(0);
    }

    if (kt + 2 < NKT) {
      asm volatile("" ::: "memory");
      __builtin_amdgcn_sched_barrier(0);
      __builtin_amdgcn_s_barrier();
      STAGE_(kt + 2, kt & 1);
    }
  }
#undef STAGE_
}

// ---- fused QKV projection: C = A @ W^T (single dispatch, z = 0/1/2) ----
// z=0 -> Q (scale pre-folded in Wqb); z=1 -> K; z=2 -> V TRANSPOSED [b][n][t]
__global__ __launch_bounds__(512, 2) void gemm_qkv(const u16* __restrict__ xq,
                                                   const u16* __restrict__ xk,
                                                   const u16* __restrict__ xv,
                                                   const u16* __restrict__ Wqb,
                                                   const u16* __restrict__ Wkb,
                                                   const u16* __restrict__ Wvb,
                                                   u16* __restrict__ Qb, u16* __restrict__ Kb,
                                                   u16* __restrict__ Vtg) {
  __shared__ u16 As[2 * ASZ];   // 64 KiB
  __shared__ u16 Bs[2 * BSZ];   // 32 KiB
  const int z = blockIdx.z;
  const u16* A = (z == 0) ? xq : (z == 1) ? xk : xv;
  const u16* B = (z == 0) ? Wqb : (z == 1) ? Wkb : Wvb;
  const int m0 = blockIdx.x * BM, n0 = blockIdx.y * BN;

  f32x4 acc[4][4];
  gemm_core(A, B, As, Bs, m0, n0, acc);

  const int lane = threadIdx.x & 63, wave = threadIdx.x >> 6;
  const int wm = wave >> 1, wn = wave & 1;
  const int lrow = lane & 15, quad = lane >> 4;

  // C/D: col = lane&15 (n), row = quad*4 + reg (m)
  if (z == 2) {
    const int b = m0 >> 11;
    const int t0 = (m0 & 2047);
#pragma unroll
    for (int i = 0; i < 4; i++) {
      const int trow = t0 + wm * 64 + i * 16 + quad * 4;
#pragma unroll
      for (int j = 0; j < 4; j++) {
        const int n = n0 + wn * 64 + j * 16 + lrow;
        ushort4 pk;
        pk.x = f2bf(acc[i][j][0]); pk.y = f2bf(acc[i][j][1]);
        pk.z = f2bf(acc[i][j][2]); pk.w = f2bf(acc[i][j][3]);
        *(ushort4*)(Vtg + (size_t)b * D_MODEL * SEQ + (size_t)n * SEQ + trow) = pk;
      }
    }
  } else {
    u16* C = z ? Kb : Qb;
#pragma unroll
    for (int i = 0; i < 4; i++) {
      const int mr = m0 + wm * 64 + i * 16 + quad * 4;
#pragma unroll
      for (int j = 0; j < 4; j++) {
        const int n = n0 + wn * 64 + j * 16 + lrow;
#pragma unroll
        for (int r = 0; r < 4; r++) C[(size_t)(mr + r) * 1024 + n] = f2bf(acc[i][j][r]);
      }
    }
  }
}

// ---- output projection: f32 out — R0 baseline 128^2 kernel (measured best) --
__global__ __launch_bounds__(256) void gemm_o(const u16* __restrict__ A,
                                              const u16* __restrict__ B,
                                              float* __restrict__ C) {
  __shared__ u16 As[128 * 64];
  __shared__ u16 Bs[128 * 64];
  const int t = threadIdx.x;
  const int lane = t & 63, wave = t >> 6;
  const int wm = wave & 1, wn = wave >> 1;
  const int lrow = lane & 15, quad = lane >> 4;
  const int m0 = blockIdx.x * 128, n0 = blockIdx.y * 128;
  const int srow = t >> 3;
  const int swcol = (((t & 7) ^ (srow & 7)) << 3);
  const int rsw = lrow & 7;

  f32x4 acc[4][4];
#pragma unroll
  for (int i = 0; i < 4; i++)
#pragma unroll
    for (int j = 0; j < 4; j++) acc[i][j] = (f32x4){0.f, 0.f, 0.f, 0.f};

  for (int k0 = 0; k0 < 1024; k0 += 64) {
#pragma unroll
    for (int r = 0; r < 4; ++r) {
      int rr = r * 32 + srow;
      gload_lds16(A + (size_t)(m0 + rr) * 1024 + k0 + swcol, As + rr * 64 + (t & 7) * 8);
      gload_lds16(B + (size_t)(n0 + rr) * 1024 + k0 + swcol, Bs + rr * 64 + (t & 7) * 8);
    }
    __syncthreads();
#pragma unroll
    for (int ks = 0; ks < 2; ++ks) {
      const int cx = ((ks * 4 + quad) ^ rsw) << 3;
      bf16x8 a[4], b[4];
#pragma unroll
      for (int i = 0; i < 4; i++)
        a[i] = *(const bf16x8*)(As + (wm * 64 + i * 16 + lrow) * 64 + cx);
#pragma unroll
      for (int j = 0; j < 4; j++)
        b[j] = *(const bf16x8*)(Bs + (wn * 64 + j * 16 + lrow) * 64 + cx);
#pragma unroll
      for (int i = 0; i < 4; i++)
#pragma unroll
        for (int j = 0; j < 4; j++) acc[i][j] = MFMA(a[i], b[j], acc[i][j]);
    }
    __syncthreads();
  }
#pragma unroll
  for (int i = 0; i < 4; i++) {
    const int mr = m0 + wm * 64 + i * 16 + quad * 4;
#pragma unroll
    for (int j = 0; j < 4; j++) {
      const int n = n0 + wn * 64 + j * 16 + lrow;
#pragma unroll
      for (int r = 0; r < 4; r++) C[(size_t)(mr + r) * 1024 + n] = acc[i][j][r];
    }
  }
}

// ---- causal flash attention, v5: occupancy rebuild ----
// Was (v4): 64 KB LDS -> 2 blocks/CU, paired-qt part loop, 512 blocks.
// attn measured 86 µs @ MfmaUtil 19%, VALU 39%, HBM 6% — latency-bound,
// nothing saturated. v5 raises TLP: K/V double-buffered (48 KB total ->
// 3 blocks/CU = 12 waves), one qt per block (grid (64,16) = 1024 blocks,
// qt = 15 - y so the 32-tile blocks launch first). Prefetch distance 1:
// stage kt+1 right after the top barrier — its buffer was last read in
// kt-1 (reads retired before each wave's kt-1 MFMAs, which precede this
// barrier), and its DMA ages a full iteration before the vmcnt(0) drain.
// Compute section and numerics unchanged from v4.
__global__ __launch_bounds__(256) void attn_causal(const u16* __restrict__ Qb,
                                                   const u16* __restrict__ Kb,
                                                   const u16* __restrict__ Vtg,
                                                   u16* __restrict__ Ob) {
  __shared__ u16 QPs[128 * 64];   // 16 KB: Q staging, then P
  __shared__ u16 Ks[2 * 64 * 64]; // 16 KB
  __shared__ u16 Vs[2 * 64 * 64]; // 16 KB  V^T tiles [d][j]

  const int t = threadIdx.x;
  const int lane = t & 63, wave = t >> 6;
  const int lrow = lane & 15, quad = lane >> 4;
  const int wb = wave * 32;
  const int bh = blockIdx.x;
  const int b = bh >> 4, h = bh & 15;
  const int col0 = h * 64;
  const size_t rowbase = (size_t)b * SEQ;
  const size_t vbase = (size_t)b * (size_t)D_MODEL * SEQ;
  const int srow = t >> 3;
  const int swcol = (((t & 7) ^ (srow & 7)) << 3);
  const int pchunk = (t & 7) * 8;
  const int rsw = lrow & 7;

#define KVSTAGE_(kt_, bi_)                                                      \
  do {                                                                          \
    const int j0_ = (kt_)*64;                                                   \
    u16* ks_ = Ks + (bi_)*4096;                                                 \
    u16* vs_ = Vs + (bi_)*4096;                                                 \
    _Pragma("unroll") for (int r_ = 0; r_ < 2; ++r_) {                          \
      int rr_ = r_ * 32 + srow;                                                 \
      gload_lds16(Kb + (rowbase + j0_ + rr_) * D_MODEL + col0 + swcol,          \
                  ks_ + rr_ * 64 + pchunk);                                     \
      gload_lds16(Vtg + vbase + (size_t)(col0 + rr_) * SEQ + j0_ + swcol,       \
                  vs_ + rr_ * 64 + pchunk);                                     \
    }                                                                           \
  } while (0)

  bf16x8 bOnes;
  {
    const short ov = (lrow == 0) ? (short)0x3F80 : (short)0;
#pragma unroll
    for (int e = 0; e < 8; ++e) bOnes[e] = ov;
  }

  const int qt = 15 - (int)blockIdx.y;   // longest blocks first
  const int qrow0 = qt * 128;
  const int nkt = 2 * qt + 2;            // >= 2

  // stage Q tile (4 DMA) + K/V tile 0 (4 DMA)
#pragma unroll
  for (int r = 0; r < 4; ++r) {
    int rr = r * 32 + srow;
    gload_lds16(Qb + (rowbase + qrow0 + rr) * D_MODEL + col0 + swcol,
                QPs + rr * 64 + pchunk);
  }
  KVSTAGE_(0, 0);

  bf16x8 bQ[2][2];
  f32x4 oacc[2][4];
  f32x4 lacc[2];
#pragma unroll
  for (int mf = 0; mf < 2; mf++) {
#pragma unroll
    for (int df = 0; df < 4; df++) oacc[mf][df] = (f32x4){0.f, 0.f, 0.f, 0.f};
    lacc[mf] = (f32x4){0.f, 0.f, 0.f, 0.f};
  }

  for (int kt = 0; kt < nkt; ++kt) {
    // in flight: tile kt's 4 DMA (issued one full iteration ago; at kt==0
    // also the Q stage) — aged drain, then one barrier.
    asm volatile("s_waitcnt vmcnt(0)" ::: "memory");
    __builtin_amdgcn_s_barrier();
    asm volatile("" ::: "memory");

    if (kt + 1 < nkt) KVSTAGE_(kt + 1, (kt + 1) & 1);  // buffer last read in kt-1

    const u16* ksb = Ks + (kt & 1) * 4096;
    const u16* vsb = Vs + (kt & 1) * 4096;

    if (kt == 0) {
#pragma unroll
      for (int mf = 0; mf < 2; ++mf)
#pragma unroll
        for (int ks = 0; ks < 2; ++ks)
          bQ[mf][ks] = *(const bf16x8*)(QPs + (wb + mf * 16 + lrow) * 64 +
                                        (((ks * 4 + quad) ^ rsw) << 3));
    }

    const int j0 = kt * 64;
    const bool diag = (kt >= 2 * qt);
    // S^T = K·Q^T per mf half; softmax; P -> QPs (ushort4, swizzled)
#pragma unroll
    for (int mf = 0; mf < 2; ++mf) {
      f32x4 st[4];
#pragma unroll
      for (int jf = 0; jf < 4; jf++) st[jf] = (f32x4){0.f, 0.f, 0.f, 0.f};
      __builtin_amdgcn_s_setprio(1);
#pragma unroll
      for (int ks = 0; ks < 2; ++ks) {
        const int cx = ((ks * 4 + quad) ^ rsw) << 3;
#pragma unroll
        for (int jf = 0; jf < 4; jf++) {
          bf16x8 aK = *(const bf16x8*)(ksb + (jf * 16 + lrow) * 64 + cx);
          st[jf] = MFMA(aK, bQ[mf][ks], st[jf]);
        }
      }
      __builtin_amdgcn_s_setprio(0);
      const int m = wb + mf * 16 + lrow;
      const int gm = qrow0 + m;
#pragma unroll
      for (int jf = 0; jf < 4; jf++) {
        ushort4 pk;
#pragma unroll
        for (int r = 0; r < 4; r++) {
          float p = __builtin_amdgcn_exp2f(st[jf][r]);  // scale pre-folded
          const int gj = j0 + jf * 16 + quad * 4 + r;
          if (diag && gj > gm) p = 0.f;
          ((u16*)&pk)[r] = f2bf_t(p);
        }
        const int j = jf * 16 + quad * 4;
        *(ushort4*)(QPs + m * 64 + ((((j >> 3) ^ (m & 7)) << 3) | (j & 7))) = pk;
      }
    }

    // O += P·V^T ; l += P·1  (QPs rows are wave-private: no barrier)
#pragma unroll
    for (int ks = 0; ks < 2; ++ks) {
      const int cx = ((ks * 4 + quad) ^ rsw) << 3;  // (m&7)==rsw for our rows
      bf16x8 aP[2];
#pragma unroll
      for (int mf = 0; mf < 2; ++mf)
        aP[mf] = *(const bf16x8*)(QPs + (wb + mf * 16 + lrow) * 64 + cx);
      __builtin_amdgcn_s_setprio(1);
      lacc[0] = MFMA(aP[0], bOnes, lacc[0]);
      lacc[1] = MFMA(aP[1], bOnes, lacc[1]);
#pragma unroll
      for (int df = 0; df < 4; df++) {
        bf16x8 bV = *(const bf16x8*)(vsb + (df * 16 + lrow) * 64 + cx);
        oacc[0][df] = MFMA(aP[0], bV, oacc[0][df]);
        oacc[1][df] = MFMA(aP[1], bV, oacc[1][df]);
      }
      __builtin_amdgcn_s_setprio(0);
    }
    __builtin_amdgcn_sched_barrier(0);  // pin iteration edge (buffer-free proof)
  }

  // l[m = quad*4+r] sits in lacc[mf][r] at lane quad*16 (col 0)
  float linv[2][4];
#pragma unroll
  for (int mf = 0; mf < 2; mf++)
#pragma unroll
    for (int r = 0; r < 4; r++)
      linv[mf][r] = 1.0f / __shfl(lacc[mf][r], lane & 48);

  // store O: row = qrow0 + wb + mf*16 + quad*4 + r, col = col0 + df*16 + lrow
#pragma unroll
  for (int mf = 0; mf < 2; mf++)
#pragma unroll
    for (int r = 0; r < 4; r++) {
      u16* orow = Ob + (rowbase + qrow0 + wb + mf * 16 + quad * 4 + r) * D_MODEL + col0;
#pragma unroll
      for (int df = 0; df < 4; df++)
        orow[df * 16 + lrow] = f2bf(oacc[mf][df][r] * linv[mf][r]);
    }
#undef KVSTAGE_
}

extern "C" void kernel_launch(void* const* d_in, const int* in_sizes, int n_in,
                              void* d_out, int out_size, void* d_ws, size_t ws_size,
                              hipStream_t stream) {
  const float* q  = (const float*)d_in[0];
  const float* k  = (const float*)d_in[1];
  const float* v  = (const float*)d_in[2];
  // d_in[3] = mask — strict-upper-triangle causal; handled analytically
  const float* Wq = (const float*)d_in[4];
  const float* Wk = (const float*)d_in[5];
  const float* Wv = (const float*)d_in[6];
  const float* Wo = (const float*)d_in[7];
  float* out = (float*)d_out;

  char* ws = (char*)d_ws;
  const size_t MB = 1 << 20;
  u16* xq  = (u16*)(ws);
  u16* xk  = (u16*)(ws + 16 * MB);
  u16* xv  = (u16*)(ws + 32 * MB);
  u16* Wqb = (u16*)(ws + 48 * MB);
  u16* Wkb = (u16*)(ws + 50 * MB);
  u16* Wvb = (u16*)(ws + 52 * MB);
  u16* Wob = (u16*)(ws + 54 * MB);
  u16* Qb  = (u16*)(ws + 56 * MB);

  const dim3 cb(256);
  const dim3 gb(512);
  cvt_all<<<dim3(28672), cb, 0, stream>>>(q, k, v, Wq, Wk, Wv, Wo,
                                          xq, xk, xv, Wqb, Wkb, Wvb, Wob);

  if (ws_size >= 104 * MB) {
    u16* Kb  = (u16*)(ws + 72 * MB);
    u16* Vtg = (u16*)(ws + 88 * MB);
    gemm_qkv<<<dim3(32, 8, 3), gb, 0, stream>>>(xq, xk, xv, Wqb, Wkb, Wvb,
                                                Qb, Kb, Vtg);
    attn_causal<<<dim3(64, 16), cb, 0, stream>>>(Qb, Kb, Vtg, xq);  // O -> xq
    gemm_o<<<dim3(64, 8), cb, 0, stream>>>(xq, Wob, out);
  } else {
    // (fallback path unused when ws >= 104 MB; kept for small workspaces)
    u16* Kb  = (u16*)(ws);
    u16* Vtg = (u16*)(ws + 16 * MB);
    u16* Oatt = (u16*)(ws + 32 * MB);
    gemm_qkv<<<dim3(32, 8, 3), gb, 0, stream>>>(xq, xk, xv, Wqb, Wkb, Wvb,
                                                Qb, Kb, Vtg);
    attn_causal<<<dim3(64, 16), cb, 0, stream>>>(Qb, Kb, Vtg, Oatt);
    gemm_o<<<dim3(64, 8), cb, 0, stream>>>(Oatt, Wob, out);
  }
}